// Round 2
// baseline (1082.655 us; speedup 1.0000x reference)
//
#include <hip/hip_runtime.h>
#include <math.h>

// Problem constants
#define DD    256      // embedding dim
#define KK    2048     // num codewords
#define BB    32       // batch
#define HW    1024     // H*W = 32*32
#define NN    32768    // BB*HW rows
#define NUMEL 8388608  // BB*DD*HW

// Workspace layout (bytes) — total 16,388 B
#define WS_E2     0        // 2048 floats
#define WS_COUNTS 8192     // 2048 ints
#define WS_LOSS   16384    // 1 float

// Output layout (floats): quantized_st | loss | perplexity | indices(as float)
#define OUT_LOSS  8388608
#define OUT_PPL   8388609
#define OUT_IDX   8388610

// --------------------------------------------------------------------------
// Kernel 1: e2[k] = sum_d emb[d][k]^2 (coalesced along k). Also zeroes the
// histogram and loss accumulator (stream-ordered before their writers).
__global__ __launch_bounds__(256) void e2_kernel(const float* __restrict__ emb,
                                                 float* __restrict__ e2,
                                                 int*   __restrict__ counts,
                                                 float* __restrict__ lossac) {
    int k = blockIdx.x * 256 + threadIdx.x;
    float s = 0.f;
    for (int d = 0; d < DD; ++d) {
        float v = emb[(size_t)d * KK + k];
        s += v * v;
    }
    e2[k] = s;
    counts[k] = 0;
    if (k == 0) *lossac = 0.f;
}

// --------------------------------------------------------------------------
// Kernel 2: fused distance-GEMM + argmin per row.
// Block: 256 threads. Tile: BM=32 rows x BN=128 cols, BK=16 d-slice.
// A panel (32 rows x 256 d, clipped) resident in LDS (32 KB); B staged 8 KB.
// score = e2[c] - 2*dot  (the x^2 term is row-constant => argmin-invariant).
// Thread (tx=tid&31, ty=tid>>5) owns rows ty*4..+3, cols tx*4..+3 of the tile.
#define BM 32
#define BN 128
#define BK 16

__global__ __launch_bounds__(256) void argmin_kernel(
    const float* __restrict__ x,    // (B, D, H, W)
    const float* __restrict__ emb,  // (D, K)
    const float* __restrict__ e2,   // (K,)
    float* __restrict__ out_idx_f,  // (N,) indices as float
    int*   __restrict__ counts)
{
    __shared__ float sA[DD][BM];    // [d][row], 32 KB
    __shared__ float sB[BK][BN];    // [dd][col], 8 KB

    const int tid = threadIdx.x;
    const int n0  = blockIdx.x * BM;      // 32 | 1024, so a tile never crosses b
    const int b   = n0 >> 10;
    const int hw0 = n0 & 1023;
    const float* xb = x + (size_t)b * DD * HW + hw0;   // xb[d*HW + r]

    // Load A panel: 32 rows x 256 d = 8192 floats, float4 along rows (coalesced)
    for (int i = 0; i < 8; ++i) {
        int idx = tid + i * 256;          // quad index 0..2047
        int d   = idx >> 3;               // 0..255
        int r4  = (idx & 7) << 2;         // 0,4,..,28
        float4 v = *(const float4*)(xb + (size_t)d * HW + r4);
        v.x = fminf(fmaxf(v.x, -10.f), 10.f);
        v.y = fminf(fmaxf(v.y, -10.f), 10.f);
        v.z = fminf(fmaxf(v.z, -10.f), 10.f);
        v.w = fminf(fmaxf(v.w, -10.f), 10.f);
        sA[d][r4 + 0] = v.x; sA[d][r4 + 1] = v.y;
        sA[d][r4 + 2] = v.z; sA[d][r4 + 3] = v.w;
    }

    const int tx = tid & 31;   // col group: cols tx*4..tx*4+3 within tile
    const int ty = tid >> 5;   // row group: rows ty*4..ty*4+3

    float bestv[4] = {1e30f, 1e30f, 1e30f, 1e30f};
    int   besti[4] = {0, 0, 0, 0};

    for (int kt = 0; kt < KK / BN; ++kt) {
        const int c0 = kt * BN;
        float acc[4][4] = {};
        for (int dt = 0; dt < DD / BK; ++dt) {
            __syncthreads();   // orders A-panel writes / prior sB reads
            // Stage B slice: 16 d x 128 c = 2048 floats, 2 float4 per thread
            for (int i = 0; i < 2; ++i) {
                int idx = tid + i * 256;      // quad index 0..511
                int ddv = idx >> 5;           // 0..15
                int c4  = (idx & 31) << 2;    // 0..124
                float4 v = *(const float4*)(emb + (size_t)(dt * BK + ddv) * KK + c0 + c4);
                sB[ddv][c4 + 0] = v.x; sB[ddv][c4 + 1] = v.y;
                sB[ddv][c4 + 2] = v.z; sB[ddv][c4 + 3] = v.w;
            }
            __syncthreads();
#pragma unroll
            for (int kk = 0; kk < BK; ++kk) {
                const float4 av = *(const float4*)&sA[dt * BK + kk][ty * 4];
                const float4 bv = *(const float4*)&sB[kk][tx * 4];
                acc[0][0] += av.x * bv.x; acc[0][1] += av.x * bv.y;
                acc[0][2] += av.x * bv.z; acc[0][3] += av.x * bv.w;
                acc[1][0] += av.y * bv.x; acc[1][1] += av.y * bv.y;
                acc[1][2] += av.y * bv.z; acc[1][3] += av.y * bv.w;
                acc[2][0] += av.z * bv.x; acc[2][1] += av.z * bv.y;
                acc[2][2] += av.z * bv.z; acc[2][3] += av.z * bv.w;
                acc[3][0] += av.w * bv.x; acc[3][1] += av.w * bv.y;
                acc[3][2] += av.w * bv.z; acc[3][3] += av.w * bv.w;
            }
        }
        // Scores + running argmin. Strict '<' keeps first occurrence; j (and
        // kt) ascend, so in-thread ties resolve to the smallest column index,
        // matching jnp.argmin semantics.
#pragma unroll
        for (int j = 0; j < 4; ++j) {
            int c = c0 + tx * 4 + j;
            float ev = e2[c];
#pragma unroll
            for (int i = 0; i < 4; ++i) {
                float s = ev - 2.f * acc[i][j];
                if (s < bestv[i]) { bestv[i] = s; besti[i] = c; }
            }
        }
    }

    // Cross-thread reduce: for each row, its 32 owners are lanes tx=0..31 of
    // one 32-lane half-wave (tid = ty*32+tx). Butterfly shfl_xor with masks
    // 16..1 stays within the half-wave. Min-index tie-break preserves
    // first-occurrence semantics.
#pragma unroll
    for (int m = 16; m >= 1; m >>= 1) {
#pragma unroll
        for (int i = 0; i < 4; ++i) {
            float ov = __shfl_xor(bestv[i], m, 64);
            int   oi = __shfl_xor(besti[i], m, 64);
            if (ov < bestv[i] || (ov == bestv[i] && oi < besti[i])) {
                bestv[i] = ov; besti[i] = oi;
            }
        }
    }
    if (tx == 0) {
#pragma unroll
        for (int i = 0; i < 4; ++i) {
            int n = n0 + ty * 4 + i;
            out_idx_f[n] = (float)besti[i];
            atomicAdd(&counts[besti[i]], 1);
        }
    }
}

// --------------------------------------------------------------------------
// Kernel 3: gather quantized values into (B,D,H,W) + fused MSE reduction.
// loss_raw accumulates sum((q - x)^2); finalize scales by 1.25/NUMEL
// (e_latent and q_latent losses are numerically identical arrays).
__global__ __launch_bounds__(256) void quant_loss_kernel(
    const float* __restrict__ x,
    const float* __restrict__ emb,
    const float* __restrict__ idxf,   // (N,) indices as float
    float* __restrict__ outq,
    float* __restrict__ loss_acc)
{
    size_t o4 = ((size_t)blockIdx.x * 256 + threadIdx.x) * 4;
    int b  = (int)(o4 >> 18);
    int d  = (int)((o4 >> 10) & 255);
    int hw = (int)(o4 & 1023);
    int n  = b * HW + hw;
    // Scalar loads (idxf base in d_out is not 16B-aligned); coalesced across
    // the block since a block covers one full (b,d) row of hw.
    int i0 = (int)idxf[n + 0];
    int i1 = (int)idxf[n + 1];
    int i2 = (int)idxf[n + 2];
    int i3 = (int)idxf[n + 3];
    // Safety clamp: a bad index becomes a wrong answer, not a memory fault.
    i0 = min(max(i0, 0), KK - 1); i1 = min(max(i1, 0), KK - 1);
    i2 = min(max(i2, 0), KK - 1); i3 = min(max(i3, 0), KK - 1);
    const float* er = emb + (size_t)d * KK;
    float4 q;
    q.x = er[i0]; q.y = er[i1]; q.z = er[i2]; q.w = er[i3];
    const float4 xv = *(const float4*)(x + o4);
    *(float4*)(outq + o4) = q;
    float ax = q.x - xv.x, ay = q.y - xv.y, az = q.z - xv.z, aw = q.w - xv.w;
    float s = ax * ax + ay * ay + az * az + aw * aw;
#pragma unroll
    for (int off = 32; off > 0; off >>= 1) s += __shfl_down(s, off, 64);
    if ((threadIdx.x & 63) == 0) atomicAdd(loss_acc, s);
}

// --------------------------------------------------------------------------
// Kernel 4: perplexity from histogram + loss finalize.
__global__ __launch_bounds__(256) void finalize_kernel(
    const int* __restrict__ counts,
    const float* __restrict__ loss_acc,
    float* __restrict__ out)
{
    __shared__ float red[4];
    int tid = threadIdx.x;
    float s = 0.f;
    for (int k = tid; k < KK; k += 256) {
        float p = (float)counts[k] * (1.0f / (float)NN);
        s += p * logf(p + 1e-10f);
    }
#pragma unroll
    for (int off = 32; off > 0; off >>= 1) s += __shfl_down(s, off, 64);
    if ((tid & 63) == 0) red[tid >> 6] = s;
    __syncthreads();
    if (tid == 0) {
        float tot = red[0] + red[1] + red[2] + red[3];
        out[OUT_PPL]  = expf(-tot);
        out[OUT_LOSS] = loss_acc[0] * 1.25f / (float)NUMEL;
    }
}

// --------------------------------------------------------------------------
extern "C" void kernel_launch(void* const* d_in, const int* in_sizes, int n_in,
                              void* d_out, int out_size, void* d_ws, size_t ws_size,
                              hipStream_t stream) {
    const float* x   = (const float*)d_in[0];
    const float* emb = (const float*)d_in[1];
    float* out = (float*)d_out;
    char*  ws  = (char*)d_ws;

    float* e2     = (float*)(ws + WS_E2);
    int*   counts = (int*)(ws + WS_COUNTS);
    float* lossac = (float*)(ws + WS_LOSS);

    e2_kernel<<<KK / 256, 256, 0, stream>>>(emb, e2, counts, lossac);
    argmin_kernel<<<NN / BM, 256, 0, stream>>>(x, emb, e2, out + OUT_IDX, counts);
    quant_loss_kernel<<<NUMEL / 1024, 256, 0, stream>>>(x, emb, out + OUT_IDX, out, lossac);
    finalize_kernel<<<1, 256, 0, stream>>>(counts, lossac, out);
}

// Round 3
// 637.660 us; speedup vs baseline: 1.6979x; 1.6979x over previous
//
#include <hip/hip_runtime.h>
#include <hip/hip_bf16.h>
#include <math.h>

typedef unsigned int  uint;
typedef unsigned short ushort;

// Problem constants
#define DD    256      // embedding dim
#define KK    2048     // num codewords
#define HW    1024     // H*W
#define NN    32768    // rows
#define NUMEL 8388608  // total elements
#define STRIDEB (DD*HW)

// Workspace layout (bytes) — total ~2.52 MB
#define WS_H2     0         // 2048 f32: 0.5*||e_k||^2
#define WS_COUNTS 8192      // 2048 i32
#define WS_LOSS   16384     // 1 f32 (padded to 128)
#define WS_EBF    16512     // emb frag-ordered bf16 hi/lo: 2 MB
#define WS_PV     2113664   // 65536 f32 partial best value  (N x 2 halves)
#define WS_PI     2375808   // 65536 i32 partial best index

// Output layout (floats): quantized_st | loss | perplexity | indices(as float)
#define OUT_LOSS  8388608
#define OUT_PPL   8388609
#define OUT_IDX   8388610

typedef __attribute__((ext_vector_type(8))) short  short8;   // 8 bf16 (4 VGPR)
typedef __attribute__((ext_vector_type(4))) float  float4v;  // 4 fp32 acc

__device__ __forceinline__ ushort f2bf(float f) {   // RNE fp32->bf16 bits
    uint u = __float_as_uint(f);
    return (ushort)((u + 0x7FFFu + ((u >> 16) & 1u)) >> 16);
}

// --------------------------------------------------------------------------
// Kernel 1: h2[k] = 0.5*sum_d emb[d][k]^2; zero counts + loss accumulator.
__global__ __launch_bounds__(256) void e2h_kernel(const float* __restrict__ emb,
                                                  float* __restrict__ h2,
                                                  int*   __restrict__ counts,
                                                  float* __restrict__ lossac) {
    int k = blockIdx.x * 256 + threadIdx.x;
    float s = 0.f;
    for (int d = 0; d < DD; ++d) {
        float v = emb[(size_t)d * KK + k];
        s += v * v;
    }
    h2[k] = 0.5f * s;
    counts[k] = 0;
    if (k == 0) *lossac = 0.f;
}

// --------------------------------------------------------------------------
// Kernel 2: reorder emb (D,K) fp32 into MFMA-B-fragment-major bf16 hi/lo.
// Element (d, k) -> plane hl, tile ct=k>>4, slice s=d>>5, lane l=((d>>3)&3)*16
// + (k&15), j=d&7. u16 offset = (((ct*8+s)*2+hl)*64 + l)*8 + j.
// 65536 threads; thread g: k = g&2047, dgroup = g>>11 (8 consecutive d).
__global__ __launch_bounds__(256) void prep_emb(const float* __restrict__ emb,
                                                ushort* __restrict__ ebf) {
    int g  = blockIdx.x * 256 + threadIdx.x;
    int k  = g & (KK - 1);
    int dg = g >> 11;          // 0..31
    int d0 = dg * 8;
    int s    = dg >> 2;
    int quad = dg & 3;
    int ct   = k >> 4;
    int l    = quad * 16 + (k & 15);

    union { ushort us[8]; uint4 v; } hu, lu;
#pragma unroll
    for (int j = 0; j < 8; ++j) {
        float v = emb[(size_t)(d0 + j) * KK + k];
        ushort hb = f2bf(v);
        float  hf = __uint_as_float(((uint)hb) << 16);
        hu.us[j] = hb;
        lu.us[j] = f2bf(v - hf);
    }
    size_t hi_off = (size_t)(((ct * 8 + s) * 2 + 0) * 64 + l) * 8;
    size_t lo_off = (size_t)(((ct * 8 + s) * 2 + 1) * 64 + l) * 8;
    *(uint4*)(ebf + hi_off) = hu.v;
    *(uint4*)(ebf + lo_off) = lu.v;
}

// --------------------------------------------------------------------------
// Kernel 3: split-bf16 MFMA distance + per-row argmin over a column half.
// Grid 512: rb = bid>>1 (128-row group), ch = bid&1 (1024-col half).
// 4 waves/block; wave owns 2 strips of 16 rows; A (x) frags in VGPRs.
// Per 16-col tile: stage 16 KB of B frags (hi+lo) to LDS, 48 MFMAs.
// score = h2[c] - dot  (== 0.5*(||e||^2 - 2 x.e); x^2 term argmin-invariant).
__global__ __launch_bounds__(256, 2) void argmin_mfma(
    const float*  __restrict__ x,
    const ushort* __restrict__ ebf,
    const float*  __restrict__ h2,
    float* __restrict__ pv,
    int*   __restrict__ pi)
{
    __shared__ ushort sB[8192];   // 16 KB: [slice s][hl][lane][j]

    const int tid  = threadIdx.x;
    const int w    = tid >> 6;
    const int lane = tid & 63;
    const int m    = lane & 15;
    const int quad = lane >> 4;

    const int rb = blockIdx.x >> 1;
    const int ch = blockIdx.x & 1;
    const int n0 = rb * 128 + w * 32;          // wave's first row
    const int b  = n0 >> 10;                   // 128 | 1024: single batch/block
    const int hwb = n0 & 1023;
    const float* xb = x + (size_t)b * STRIDEB;

    // ---- Build A fragments in registers: 2 strips x 8 slices x (hi,lo) ----
    // A[m=lane&15][k=quad*8+j] for slice s => d = s*32 + quad*8 + j.
    short8 xh[2][8], xl[2][8];
#pragma unroll
    for (int st = 0; st < 2; ++st) {
        const int hw = hwb + st * 16 + m;
#pragma unroll
        for (int s = 0; s < 8; ++s) {
            const float* p = xb + (size_t)(s * 32 + quad * 8) * HW + hw;
            short8 hh, ll;
#pragma unroll
            for (int j = 0; j < 8; ++j) {
                float v = p[(size_t)j * HW];
                v = fminf(fmaxf(v, -10.f), 10.f);
                ushort hb = f2bf(v);
                float  hf = __uint_as_float(((uint)hb) << 16);
                hh[j] = (short)hb;
                ll[j] = (short)f2bf(v - hf);
            }
            xh[st][s] = hh;
            xl[st][s] = ll;
        }
    }

    float bv[2][4] = {{1e30f,1e30f,1e30f,1e30f},{1e30f,1e30f,1e30f,1e30f}};
    int   bi[2][4] = {{0,0,0,0},{0,0,0,0}};
    const int cbase = ch * 1024;

    for (int ct = 0; ct < 64; ++ct) {
        const int ctg = (cbase >> 4) + ct;
        __syncthreads();   // protect sB from prior iteration's readers
        {   // stage 16 KB (coalesced 16B/lane; LDS 2-way aliasing = free)
            const uint4* gsrc = (const uint4*)(ebf + (size_t)ctg * 8192);
            uint4* ldst = (uint4*)sB;
#pragma unroll
            for (int i = 0; i < 4; ++i) ldst[tid + i * 256] = gsrc[tid + i * 256];
        }
        __syncthreads();

        float4v ahh0 = {0,0,0,0}, ahl0 = {0,0,0,0}, alh0 = {0,0,0,0};
        float4v ahh1 = {0,0,0,0}, ahl1 = {0,0,0,0}, alh1 = {0,0,0,0};
#pragma unroll
        for (int s = 0; s < 8; ++s) {
            short8 eh = *(const short8*)&sB[(s * 2 + 0) * 512 + lane * 8];
            short8 el = *(const short8*)&sB[(s * 2 + 1) * 512 + lane * 8];
            alh0 = __builtin_amdgcn_mfma_f32_16x16x32_bf16(xl[0][s], eh, alh0, 0, 0, 0);
            ahl0 = __builtin_amdgcn_mfma_f32_16x16x32_bf16(xh[0][s], el, ahl0, 0, 0, 0);
            ahh0 = __builtin_amdgcn_mfma_f32_16x16x32_bf16(xh[0][s], eh, ahh0, 0, 0, 0);
            alh1 = __builtin_amdgcn_mfma_f32_16x16x32_bf16(xl[1][s], eh, alh1, 0, 0, 0);
            ahl1 = __builtin_amdgcn_mfma_f32_16x16x32_bf16(xh[1][s], el, ahl1, 0, 0, 0);
            ahh1 = __builtin_amdgcn_mfma_f32_16x16x32_bf16(xh[1][s], eh, ahh1, 0, 0, 0);
        }
        // C layout: col = lane&15 (codeword), row = quad*4 + reg (query row).
        const int c  = cbase + ct * 16 + m;
        const float hv = h2[c];
#pragma unroll
        for (int i = 0; i < 4; ++i) {
            float s0 = hv - (ahh0[i] + (ahl0[i] + alh0[i]));
            float s1 = hv - (ahh1[i] + (ahl1[i] + alh1[i]));
            if (s0 < bv[0][i]) { bv[0][i] = s0; bi[0][i] = c; }
            if (s1 < bv[1][i]) { bv[1][i] = s1; bi[1][i] = c; }
        }
    }

    // ---- Reduce across the 16 lanes of each quad (masks 8..1 stay inside).
#pragma unroll
    for (int st = 0; st < 2; ++st) {
#pragma unroll
        for (int i = 0; i < 4; ++i) {
            float v  = bv[st][i];
            int   ix = bi[st][i];
#pragma unroll
            for (int msk = 8; msk >= 1; msk >>= 1) {
                float ov = __shfl_xor(v, msk, 64);
                int   oi = __shfl_xor(ix, msk, 64);
                if (ov < v || (ov == v && oi < ix)) { v = ov; ix = oi; }
            }
            if (m == 0) {
                int n = n0 + st * 16 + quad * 4 + i;
                pv[n * 2 + ch] = v;
                pi[n * 2 + ch] = ix;
            }
        }
    }
}

// --------------------------------------------------------------------------
// Kernel 4: merge the two column halves; emit index + histogram.
// Tie -> half 0 (its indices are smaller; within-half ties already min-index).
__global__ __launch_bounds__(256) void merge_kernel(
    const float* __restrict__ pv, const int* __restrict__ pi,
    float* __restrict__ out_idx_f, int* __restrict__ counts)
{
    int n = blockIdx.x * 256 + threadIdx.x;
    float v0 = pv[n * 2 + 0], v1 = pv[n * 2 + 1];
    int   i0 = pi[n * 2 + 0], i1 = pi[n * 2 + 1];
    int ix = (v1 < v0) ? i1 : i0;
    ix = min(max(ix, 0), KK - 1);   // safety: bug -> wrong answer, not fault
    out_idx_f[n] = (float)ix;
    atomicAdd(&counts[ix], 1);
}

// --------------------------------------------------------------------------
// Kernel 5: gather quantized values into (B,D,H,W) + fused MSE reduction.
__global__ __launch_bounds__(256) void quant_loss_kernel(
    const float* __restrict__ x,
    const float* __restrict__ emb,
    const float* __restrict__ idxf,
    float* __restrict__ outq,
    float* __restrict__ loss_acc)
{
    size_t o4 = ((size_t)blockIdx.x * 256 + threadIdx.x) * 4;
    int b  = (int)(o4 >> 18);
    int d  = (int)((o4 >> 10) & 255);
    int n  = b * HW + (int)(o4 & 1023);
    int i0 = (int)idxf[n + 0];
    int i1 = (int)idxf[n + 1];
    int i2 = (int)idxf[n + 2];
    int i3 = (int)idxf[n + 3];
    i0 = min(max(i0, 0), KK - 1); i1 = min(max(i1, 0), KK - 1);
    i2 = min(max(i2, 0), KK - 1); i3 = min(max(i3, 0), KK - 1);
    const float* er = emb + (size_t)d * KK;
    float4 q;
    q.x = er[i0]; q.y = er[i1]; q.z = er[i2]; q.w = er[i3];
    const float4 xv = *(const float4*)(x + o4);
    *(float4*)(outq + o4) = q;
    float ax = q.x - xv.x, ay = q.y - xv.y, az = q.z - xv.z, aw = q.w - xv.w;
    float s = ax * ax + ay * ay + az * az + aw * aw;
#pragma unroll
    for (int off = 32; off > 0; off >>= 1) s += __shfl_down(s, off, 64);
    if ((threadIdx.x & 63) == 0) atomicAdd(loss_acc, s);
}

// --------------------------------------------------------------------------
// Kernel 6: perplexity from histogram + loss finalize.
__global__ __launch_bounds__(256) void finalize_kernel(
    const int* __restrict__ counts,
    const float* __restrict__ loss_acc,
    float* __restrict__ out)
{
    __shared__ float red[4];
    int tid = threadIdx.x;
    float s = 0.f;
    for (int k = tid; k < KK; k += 256) {
        float p = (float)counts[k] * (1.0f / (float)NN);
        s += p * logf(p + 1e-10f);
    }
#pragma unroll
    for (int off = 32; off > 0; off >>= 1) s += __shfl_down(s, off, 64);
    if ((tid & 63) == 0) red[tid >> 6] = s;
    __syncthreads();
    if (tid == 0) {
        float tot = red[0] + red[1] + red[2] + red[3];
        out[OUT_PPL]  = expf(-tot);
        out[OUT_LOSS] = loss_acc[0] * 1.25f / (float)NUMEL;
    }
}

// --------------------------------------------------------------------------
extern "C" void kernel_launch(void* const* d_in, const int* in_sizes, int n_in,
                              void* d_out, int out_size, void* d_ws, size_t ws_size,
                              hipStream_t stream) {
    const float* x   = (const float*)d_in[0];
    const float* emb = (const float*)d_in[1];
    float* out = (float*)d_out;
    char*  ws  = (char*)d_ws;

    float*  h2     = (float*)(ws + WS_H2);
    int*    counts = (int*)(ws + WS_COUNTS);
    float*  lossac = (float*)(ws + WS_LOSS);
    ushort* ebf    = (ushort*)(ws + WS_EBF);
    float*  pv     = (float*)(ws + WS_PV);
    int*    pi     = (int*)(ws + WS_PI);

    e2h_kernel<<<KK / 256, 256, 0, stream>>>(emb, h2, counts, lossac);
    prep_emb<<<256, 256, 0, stream>>>(emb, ebf);
    argmin_mfma<<<512, 256, 0, stream>>>(x, ebf, h2, pv, pi);
    merge_kernel<<<NN / 256, 256, 0, stream>>>(pv, pi, out + OUT_IDX, counts);
    quant_loss_kernel<<<NUMEL / 1024, 256, 0, stream>>>(x, emb, out + OUT_IDX, out, lossac);
    finalize_kernel<<<1, 256, 0, stream>>>(counts, lossac, out);
}

// Round 4
// 233.450 us; speedup vs baseline: 4.6376x; 2.7315x over previous
//
#include <hip/hip_runtime.h>
#include <hip/hip_bf16.h>
#include <math.h>

typedef unsigned int  uint;
typedef unsigned short ushort;

// Problem constants
#define DD    256      // embedding dim
#define KK    2048     // num codewords
#define HW    1024     // H*W
#define NN    32768    // rows
#define NUMEL 8388608  // total elements
#define STRIDEB (DD*HW)
#define NBLK_QL (NUMEL/1024)   // 8192 quant_loss blocks

// Workspace layout (bytes) — total ~2.64 MB
#define WS_H2     0         // 2048 f32: 0.5*||e_k||^2
#define WS_COUNTS 8192      // 2048 i32
#define WS_LOSS   16384     // (unused scratch, kept for layout stability)
#define WS_EBF    16512     // emb frag-ordered bf16 hi/lo: 2 MB
#define WS_PV     2113664   // 65536 f32 partial best value  (N x 2 halves)
#define WS_PI     2375808   // 65536 i32 partial best index
// Block partials for the loss reuse the PV region: pv/pi are dead after
// merge_kernel, and quant_loss_kernel runs after it (stream-ordered).
#define WS_BPART  WS_PV     // 8192 f32

// Output layout (floats): quantized_st | loss | perplexity | indices(as float)
#define OUT_LOSS  8388608
#define OUT_PPL   8388609
#define OUT_IDX   8388610

typedef __attribute__((ext_vector_type(8))) short  short8;   // 8 bf16 (4 VGPR)
typedef __attribute__((ext_vector_type(4))) float  float4v;  // 4 fp32 acc

__device__ __forceinline__ ushort f2bf(float f) {   // RNE fp32->bf16 bits
    uint u = __float_as_uint(f);
    return (ushort)((u + 0x7FFFu + ((u >> 16) & 1u)) >> 16);
}

// --------------------------------------------------------------------------
// Kernel 1: h2[k] = 0.5*sum_d emb[d][k]^2; zero the histogram.
__global__ __launch_bounds__(256) void e2h_kernel(const float* __restrict__ emb,
                                                  float* __restrict__ h2,
                                                  int*   __restrict__ counts) {
    int k = blockIdx.x * 256 + threadIdx.x;
    float s = 0.f;
    for (int d = 0; d < DD; ++d) {
        float v = emb[(size_t)d * KK + k];
        s += v * v;
    }
    h2[k] = 0.5f * s;
    counts[k] = 0;
}

// --------------------------------------------------------------------------
// Kernel 2: reorder emb (D,K) fp32 into MFMA-B-fragment-major bf16 hi/lo.
__global__ __launch_bounds__(256) void prep_emb(const float* __restrict__ emb,
                                                ushort* __restrict__ ebf) {
    int g  = blockIdx.x * 256 + threadIdx.x;
    int k  = g & (KK - 1);
    int dg = g >> 11;          // 0..31
    int d0 = dg * 8;
    int s    = dg >> 2;
    int quad = dg & 3;
    int ct   = k >> 4;
    int l    = quad * 16 + (k & 15);

    union { ushort us[8]; uint4 v; } hu, lu;
#pragma unroll
    for (int j = 0; j < 8; ++j) {
        float v = emb[(size_t)(d0 + j) * KK + k];
        ushort hb = f2bf(v);
        float  hf = __uint_as_float(((uint)hb) << 16);
        hu.us[j] = hb;
        lu.us[j] = f2bf(v - hf);
    }
    size_t hi_off = (size_t)(((ct * 8 + s) * 2 + 0) * 64 + l) * 8;
    size_t lo_off = (size_t)(((ct * 8 + s) * 2 + 1) * 64 + l) * 8;
    *(uint4*)(ebf + hi_off) = hu.v;
    *(uint4*)(ebf + lo_off) = lu.v;
}

// --------------------------------------------------------------------------
// Kernel 3: split-bf16 MFMA distance + per-row argmin over a column half.
__global__ __launch_bounds__(256, 2) void argmin_mfma(
    const float*  __restrict__ x,
    const ushort* __restrict__ ebf,
    const float*  __restrict__ h2,
    float* __restrict__ pv,
    int*   __restrict__ pi)
{
    __shared__ ushort sB[8192];   // 16 KB: [slice s][hl][lane][j]

    const int tid  = threadIdx.x;
    const int w    = tid >> 6;
    const int lane = tid & 63;
    const int m    = lane & 15;
    const int quad = lane >> 4;

    const int rb = blockIdx.x >> 1;
    const int ch = blockIdx.x & 1;
    const int n0 = rb * 128 + w * 32;          // wave's first row
    const int b  = n0 >> 10;
    const int hwb = n0 & 1023;
    const float* xb = x + (size_t)b * STRIDEB;

    // A fragments in registers: 2 strips x 8 slices x (hi,lo).
    short8 xh[2][8], xl[2][8];
#pragma unroll
    for (int st = 0; st < 2; ++st) {
        const int hw = hwb + st * 16 + m;
#pragma unroll
        for (int s = 0; s < 8; ++s) {
            const float* p = xb + (size_t)(s * 32 + quad * 8) * HW + hw;
            short8 hh, ll;
#pragma unroll
            for (int j = 0; j < 8; ++j) {
                float v = p[(size_t)j * HW];
                v = fminf(fmaxf(v, -10.f), 10.f);
                ushort hb = f2bf(v);
                float  hf = __uint_as_float(((uint)hb) << 16);
                hh[j] = (short)hb;
                ll[j] = (short)f2bf(v - hf);
            }
            xh[st][s] = hh;
            xl[st][s] = ll;
        }
    }

    float bv[2][4] = {{1e30f,1e30f,1e30f,1e30f},{1e30f,1e30f,1e30f,1e30f}};
    int   bi[2][4] = {{0,0,0,0},{0,0,0,0}};
    const int cbase = ch * 1024;

    for (int ct = 0; ct < 64; ++ct) {
        const int ctg = (cbase >> 4) + ct;
        __syncthreads();
        {   // stage 16 KB (coalesced 16B/lane)
            const uint4* gsrc = (const uint4*)(ebf + (size_t)ctg * 8192);
            uint4* ldst = (uint4*)sB;
#pragma unroll
            for (int i = 0; i < 4; ++i) ldst[tid + i * 256] = gsrc[tid + i * 256];
        }
        __syncthreads();

        float4v ahh0 = {0,0,0,0}, ahl0 = {0,0,0,0}, alh0 = {0,0,0,0};
        float4v ahh1 = {0,0,0,0}, ahl1 = {0,0,0,0}, alh1 = {0,0,0,0};
#pragma unroll
        for (int s = 0; s < 8; ++s) {
            short8 eh = *(const short8*)&sB[(s * 2 + 0) * 512 + lane * 8];
            short8 el = *(const short8*)&sB[(s * 2 + 1) * 512 + lane * 8];
            alh0 = __builtin_amdgcn_mfma_f32_16x16x32_bf16(xl[0][s], eh, alh0, 0, 0, 0);
            ahl0 = __builtin_amdgcn_mfma_f32_16x16x32_bf16(xh[0][s], el, ahl0, 0, 0, 0);
            ahh0 = __builtin_amdgcn_mfma_f32_16x16x32_bf16(xh[0][s], eh, ahh0, 0, 0, 0);
            alh1 = __builtin_amdgcn_mfma_f32_16x16x32_bf16(xl[1][s], eh, alh1, 0, 0, 0);
            ahl1 = __builtin_amdgcn_mfma_f32_16x16x32_bf16(xh[1][s], el, ahl1, 0, 0, 0);
            ahh1 = __builtin_amdgcn_mfma_f32_16x16x32_bf16(xh[1][s], eh, ahh1, 0, 0, 0);
        }
        const int c  = cbase + ct * 16 + m;
        const float hv = h2[c];
#pragma unroll
        for (int i = 0; i < 4; ++i) {
            float s0 = hv - (ahh0[i] + (ahl0[i] + alh0[i]));
            float s1 = hv - (ahh1[i] + (ahl1[i] + alh1[i]));
            if (s0 < bv[0][i]) { bv[0][i] = s0; bi[0][i] = c; }
            if (s1 < bv[1][i]) { bv[1][i] = s1; bi[1][i] = c; }
        }
    }

#pragma unroll
    for (int st = 0; st < 2; ++st) {
#pragma unroll
        for (int i = 0; i < 4; ++i) {
            float v  = bv[st][i];
            int   ix = bi[st][i];
#pragma unroll
            for (int msk = 8; msk >= 1; msk >>= 1) {
                float ov = __shfl_xor(v, msk, 64);
                int   oi = __shfl_xor(ix, msk, 64);
                if (ov < v || (ov == v && oi < ix)) { v = ov; ix = oi; }
            }
            if (m == 0) {
                int n = n0 + st * 16 + quad * 4 + i;
                pv[n * 2 + ch] = v;
                pi[n * 2 + ch] = ix;
            }
        }
    }
}

// --------------------------------------------------------------------------
// Kernel 4: merge the two column halves; emit index + histogram.
__global__ __launch_bounds__(256) void merge_kernel(
    const float* __restrict__ pv, const int* __restrict__ pi,
    float* __restrict__ out_idx_f, int* __restrict__ counts)
{
    int n = blockIdx.x * 256 + threadIdx.x;
    float v0 = pv[n * 2 + 0], v1 = pv[n * 2 + 1];
    int   i0 = pi[n * 2 + 0], i1 = pi[n * 2 + 1];
    int ix = (v1 < v0) ? i1 : i0;
    ix = min(max(ix, 0), KK - 1);   // safety: bug -> wrong answer, not fault
    out_idx_f[n] = (float)ix;
    atomicAdd(&counts[ix], 1);
}

// --------------------------------------------------------------------------
// Kernel 5: gather quantized values + MSE reduction. NO global atomics:
// per-wave shfl reduce -> LDS -> one plain store per block (bpart[bid]).
// (R3 post-mortem: 32768 same-address float atomics serialized at ~31 cyc
// each = 420 us with VALUBusy 1%. Never again.)
__global__ __launch_bounds__(256) void quant_loss_kernel(
    const float* __restrict__ x,
    const float* __restrict__ emb,
    const float* __restrict__ idxf,
    float* __restrict__ outq,
    float* __restrict__ bpart)
{
    __shared__ float red[4];
    size_t o4 = ((size_t)blockIdx.x * 256 + threadIdx.x) * 4;
    int b  = (int)(o4 >> 18);
    int d  = (int)((o4 >> 10) & 255);
    int n  = b * HW + (int)(o4 & 1023);
    int i0 = (int)idxf[n + 0];
    int i1 = (int)idxf[n + 1];
    int i2 = (int)idxf[n + 2];
    int i3 = (int)idxf[n + 3];
    i0 = min(max(i0, 0), KK - 1); i1 = min(max(i1, 0), KK - 1);
    i2 = min(max(i2, 0), KK - 1); i3 = min(max(i3, 0), KK - 1);
    const float* er = emb + (size_t)d * KK;
    float4 q;
    q.x = er[i0]; q.y = er[i1]; q.z = er[i2]; q.w = er[i3];
    const float4 xv = *(const float4*)(x + o4);
    *(float4*)(outq + o4) = q;
    float ax = q.x - xv.x, ay = q.y - xv.y, az = q.z - xv.z, aw = q.w - xv.w;
    float s = ax * ax + ay * ay + az * az + aw * aw;
#pragma unroll
    for (int off = 32; off > 0; off >>= 1) s += __shfl_down(s, off, 64);
    if ((threadIdx.x & 63) == 0) red[threadIdx.x >> 6] = s;
    __syncthreads();
    if (threadIdx.x == 0)
        bpart[blockIdx.x] = red[0] + red[1] + red[2] + red[3];
}

// --------------------------------------------------------------------------
// Kernel 6: perplexity from histogram + loss from block partials.
__global__ __launch_bounds__(256) void finalize_kernel(
    const int* __restrict__ counts,
    const float* __restrict__ bpart,
    float* __restrict__ out)
{
    __shared__ float redp[4], redl[4];
    int tid = threadIdx.x;
    float s = 0.f;
    for (int k = tid; k < KK; k += 256) {
        float p = (float)counts[k] * (1.0f / (float)NN);
        s += p * logf(p + 1e-10f);
    }
    float ls = 0.f;
    for (int k = tid; k < NBLK_QL; k += 256) ls += bpart[k];
#pragma unroll
    for (int off = 32; off > 0; off >>= 1) {
        s  += __shfl_down(s, off, 64);
        ls += __shfl_down(ls, off, 64);
    }
    if ((tid & 63) == 0) { redp[tid >> 6] = s; redl[tid >> 6] = ls; }
    __syncthreads();
    if (tid == 0) {
        float tot = redp[0] + redp[1] + redp[2] + redp[3];
        float lsum = redl[0] + redl[1] + redl[2] + redl[3];
        out[OUT_PPL]  = expf(-tot);
        out[OUT_LOSS] = lsum * 1.25f / (float)NUMEL;
    }
}

// --------------------------------------------------------------------------
extern "C" void kernel_launch(void* const* d_in, const int* in_sizes, int n_in,
                              void* d_out, int out_size, void* d_ws, size_t ws_size,
                              hipStream_t stream) {
    const float* x   = (const float*)d_in[0];
    const float* emb = (const float*)d_in[1];
    float* out = (float*)d_out;
    char*  ws  = (char*)d_ws;

    float*  h2     = (float*)(ws + WS_H2);
    int*    counts = (int*)(ws + WS_COUNTS);
    ushort* ebf    = (ushort*)(ws + WS_EBF);
    float*  pv     = (float*)(ws + WS_PV);
    int*    pi     = (int*)(ws + WS_PI);
    float*  bpart  = (float*)(ws + WS_BPART);   // aliases pv (dead after merge)

    e2h_kernel<<<KK / 256, 256, 0, stream>>>(emb, h2, counts);
    prep_emb<<<256, 256, 0, stream>>>(emb, ebf);
    argmin_mfma<<<512, 256, 0, stream>>>(x, ebf, h2, pv, pi);
    merge_kernel<<<NN / 256, 256, 0, stream>>>(pv, pi, out + OUT_IDX, counts);
    quant_loss_kernel<<<NBLK_QL, 256, 0, stream>>>(x, emb, out + OUT_IDX, out, bpart);
    finalize_kernel<<<1, 256, 0, stream>>>(counts, bpart, out);
}